// Round 13
// baseline (283.983 us; speedup 1.0000x reference)
//
#include <hip/hip_runtime.h>

#define HASH_BITS 19
#define HASH_SIZE (1u << HASH_BITS)
#define HASH_MASK (HASH_SIZE - 1)
#define EMPTY64 0xFFFFFFFFFFFFFFFFull
#define CH 256
#define PCH 32       // pairs per chunk in bucketed sparse kernels
#define NREP 8       // counter/bucket replicas (atomic de-contention)
#define NSEG (27 * NREP)
#define SEGCAP 4096  // pairs per (k,rep) segment
#define BM_WORDS 536704  // ceil(258^3 / 32), padded

typedef __attribute__((ext_vector_type(8))) short short8;
typedef __attribute__((ext_vector_type(4))) float floatx4;
typedef unsigned long long ull;

// packed f32x2 -> bf16x2 (src0 in low half) via HW cvt
__device__ __forceinline__ unsigned cvt_pk_bf16(float a, float b) {
    unsigned r;
    asm("v_cvt_pk_bf16_f32 %0, %1, %2" : "=v"(r) : "v"(a), "v"(b));
    return r;
}

// split 8 fp32 -> packed bf16 hi + bf16 lo (x ~= hi + lo; lo compensates hi's rounding)
__device__ inline void split8_pack(const float* xa, uint4& hv, uint4& lv) {
#pragma unroll
    for (int p = 0; p < 4; ++p) {
        unsigned hp = cvt_pk_bf16(xa[2 * p], xa[2 * p + 1]);
        float h0 = __uint_as_float(hp << 16);
        float h1 = __uint_as_float(hp & 0xFFFF0000u);
        unsigned lp = cvt_pk_bf16(xa[2 * p] - h0, xa[2 * p + 1] - h1);
        ((unsigned*)&hv)[p] = hp;
        ((unsigned*)&lv)[p] = lp;
    }
}

// barrier that does NOT drain vmcnt: register-destined prefetches stay in flight.
// lgkmcnt(0) makes this wave's ds_writes visible; sched_barrier pins LDS reads
// from moving above the s_barrier (rule #18).
__device__ __forceinline__ void softbar() {
    asm volatile("s_waitcnt lgkmcnt(0)" ::: "memory");
    __builtin_amdgcn_s_barrier();
    __builtin_amdgcn_sched_barrier(0);
}

// ---------------- hash build: fused (key<<32 | idx) single-load table ----------------
__global__ void hash_insert_k(const int* __restrict__ coords, int n,
                              ull* __restrict__ tbl, unsigned* __restrict__ keys,
                              unsigned* __restrict__ bm) {
    int i = blockIdx.x * blockDim.x + threadIdx.x;
    if (i >= n) return;
    unsigned cx = (unsigned)(coords[3 * i + 0] + 1);
    unsigned cy = (unsigned)(coords[3 * i + 1] + 1);
    unsigned cz = (unsigned)(coords[3 * i + 2] + 1);
    unsigned key = (cx * 258u + cy) * 258u + cz;
    keys[i] = key;
    atomicOr(&bm[key >> 5], 1u << (key & 31));
    ull e = ((ull)key << 32) | (unsigned)i;
    unsigned h = (key * 2654435761u) & HASH_MASK;
    while (true) {
        ull prev = atomicCAS(&tbl[h], EMPTY64, e);
        if (prev == EMPTY64) return;
        h = (h + 1) & HASH_MASK;
    }
}

// ---------------- neighbor pairs: bitmap prefilter, replicated counters ----------------
__global__ void neighbor_bm_k(const unsigned* __restrict__ keys, int n,
                              const unsigned* __restrict__ bm,
                              const ull* __restrict__ tbl,
                              int2* __restrict__ buckets, int* __restrict__ kcnt) {
    int t = blockIdx.x * blockDim.x + threadIdx.x;
    if (t >= n * 9) return;
    int rep = blockIdx.x & (NREP - 1);
    int i = t / 9, r = t - i * 9;            // r = (dx+1)*3 + (dy+1)
    unsigned key = keys[i];
    int base = (int)key + ((r / 3 - 1) * 258 + (r % 3 - 1)) * 258;
    unsigned bA = base - 1, bB = base, bC = base + 1;
    unsigned hit0 = (bm[bA >> 5] >> (bA & 31)) & 1u;
    unsigned hit1 = (bm[bB >> 5] >> (bB & 31)) & 1u;
    unsigned hit2 = (bm[bC >> 5] >> (bC & 31)) & 1u;
#pragma unroll
    for (int dz = -1; dz <= 1; ++dz) {
        if (r == 4 && dz == 0) continue;     // center handled densely
        unsigned hit = dz < 0 ? hit0 : (dz == 0 ? hit1 : hit2);
        if (!hit) continue;
        unsigned nk = (unsigned)(base + dz);
        unsigned h = (nk * 2654435761u) & HASH_MASK;
        int j = -1;
        while (true) {
            ull e = tbl[h];
            if ((unsigned)(e >> 32) == nk) { j = (int)(e & 0xFFFFFFFFu); break; }
            if (e == EMPTY64) break;
            h = (h + 1) & HASH_MASK;
        }
        if (j >= 0) {
            int kk = 3 * r + dz + 1;
            int seg = kk * NREP + rep;
            int pos = atomicAdd(&kcnt[seg * 16], 1);
            buckets[(size_t)seg * SEGCAP + pos] = make_int2(i, j);
        }
    }
}

// ---------------- chunk descriptors over NSEG segments ----------------
__global__ void chunk_desc_k(const int* __restrict__ kcnt,
                             int2* __restrict__ desc, int* __restrict__ nchunks) {
    __shared__ int cnts[NSEG];
    __shared__ int offs[NSEG + 1];
    int t = threadIdx.x;
    if (t < NSEG) cnts[t] = kcnt[t * 16];
    __syncthreads();
    if (t == 0) {
        int acc = 0;
        for (int s = 0; s < NSEG; ++s) { offs[s] = acc; acc += (cnts[s] + PCH - 1) / PCH; }
        offs[NSEG] = acc;
        *nchunks = acc;
    }
    __syncthreads();
    if (t < NSEG) {
        int cnt = cnts[t];
        int o = offs[t];
        int k = t / NREP;
        for (int c = 0; c * PCH < cnt; ++c) {
            int len = min(PCH, cnt - c * PCH);
            desc[o + c] = make_int2(t * SEGCAP + c * PCH, (k << 8) | len);
        }
    }
}

// ---------------- pre-split W2+W3 (27 slices each) into fragment-ordered bf16 images ----
// image layout: [k(27)][kk(8)][nt(16)][lane(64)][j(8)] shorts
__global__ void prep_w_all_k(const float* __restrict__ W2, const float* __restrict__ W3,
                             unsigned short* __restrict__ Whi2, unsigned short* __restrict__ Wlo2,
                             unsigned short* __restrict__ Whi3, unsigned short* __restrict__ Wlo3) {
    int t = blockIdx.x * 256 + threadIdx.x;
    const int HALF = 27 * 8 * 256;
    if (t >= 2 * HALF) return;
    const float* W = (t < HALF) ? W2 : W3;
    unsigned short* Whi = (t < HALF) ? Whi2 : Whi3;
    unsigned short* Wlo = (t < HALF) ? Wlo2 : Wlo3;
    int tt = (t < HALF) ? t : t - HALF;
    int cout = tt & 255, kk = (tt >> 8) & 7, k = tt >> 11;
    int nt = cout >> 4, lc = cout & 15;
    const float* src = W + (size_t)k * 65536 + (size_t)kk * 32 * 256 + cout;
    size_t dbase = (((size_t)(k * 8 + kk) * 16 + nt) * 64 + lc) * 8;
#pragma unroll
    for (int kg = 0; kg < 4; ++kg) {
        float xa[8];
#pragma unroll
        for (int j = 0; j < 8; ++j) xa[j] = src[(size_t)(kg * 8 + j) * 256];
        uint4 hv, lv;
        split8_pack(xa, hv, lv);
        *(uint4*)(Whi + dbase + (size_t)kg * 16 * 8) = hv;
        *(uint4*)(Wlo + dbase + (size_t)kg * 16 * 8) = lv;
    }
}

// ---------------- layer 1: Cin=2 -> 256, dense center ----------------
__global__ void dense1_k(const float* __restrict__ x, const float* __restrict__ Wc,
                         float* __restrict__ out, int n) {
    int t = blockIdx.x * blockDim.x + threadIdx.x;
    if (t >= n * CH) return;
    int i = t >> 8, co = t & 255;
    float2 xv = *reinterpret_cast<const float2*>(x + 2 * i);
    out[t] = fmaf(xv.x, Wc[co], xv.y * Wc[CH + co]);
}

__global__ void sparse1b_k(const float* __restrict__ feats, const float* __restrict__ W1,
                           float* __restrict__ out, const int2* __restrict__ buckets,
                           const int2* __restrict__ desc, const int* __restrict__ nchunks) {
    __shared__ float xs[PCH][2];
    __shared__ int ii[PCH];
    int nc = *nchunks;
    int t = threadIdx.x;
    for (int m = blockIdx.x; m < nc; m += gridDim.x) {
        int2 d = desc[m];
        int k = d.y >> 8, len = d.y & 255;
        if (t < PCH) {
            if (t < len) {
                int2 pr = buckets[d.x + t];
                ii[t] = pr.x;
                xs[t][0] = feats[2 * pr.y];
                xs[t][1] = feats[2 * pr.y + 1];
            } else {
                ii[t] = -1;
                xs[t][0] = 0.f; xs[t][1] = 0.f;
            }
        }
        __syncthreads();
        const float* Wk = W1 + (size_t)k * 2 * CH;
        float w0 = Wk[t], w1 = Wk[CH + t];
#pragma unroll
        for (int p = 0; p < PCH; ++p) {
            int i = ii[p];
            if (i >= 0) atomicAdd(&out[(size_t)i * CH + t], fmaf(xs[p][0], w0, xs[p][1] * w1));
        }
        __syncthreads();
    }
}

// ---------------- mid layers dense center: M=64, A triple-buffer, soft barriers ----------
// R10 structure + counted-vmcnt barriers: __syncthreads drains vmcnt(0) (kills the
// B/x register prefetches); softbar keeps them in flight (T4).
__global__ __launch_bounds__(256, 3) void dense_mid_mfma_k(
        const float* __restrict__ x,
        const unsigned short* __restrict__ Whi,
        const unsigned short* __restrict__ Wlo,
        float* __restrict__ out, int n) {
    __shared__ unsigned short AsH[3][2048], AsL[3][2048];
    int t = threadIdx.x;
    int wid = t >> 6, lane = t & 63;
    int i0 = blockIdx.x * 64;

    floatx4 acc[4][4];
#pragma unroll
    for (int a = 0; a < 4; ++a)
#pragma unroll
        for (int b = 0; b < 4; ++b) acc[a][b] = floatx4{0.f, 0.f, 0.f, 0.f};

    // staging role: thread t -> slot t: row = (t>>6)*16 + (t&15), kg = (t>>4)&3
    int row = ((t >> 6) << 4) + (t & 15);
    int kg = (t >> 4) & 3;
    float sok = (i0 + row < n) ? 1.f : 0.f;
    const float* sp = x + (size_t)min(i0 + row, n - 1) * CH + kg * 8;

    floatx4 ra0, ra1;
    short8 Bh[2][4], Bl[2][4];

    auto loadB = [&](int kk, int b) {
#pragma unroll
        for (int q = 0; q < 4; ++q) {
            size_t off = (((size_t)kk * 16 + wid * 4 + q) * 64 + lane) * 8;
            Bh[b][q] = *(const short8*)&Whi[off];
            Bl[b][q] = *(const short8*)&Wlo[off];
        }
    };
    auto loadA = [&](int kk) {
        ra0 = *(const floatx4*)(sp + kk * 32);
        ra1 = *(const floatx4*)(sp + kk * 32 + 4);
    };
    auto writeA = [&](int bi) {
        float xa[8];
        xa[0] = ra0.x * sok; xa[1] = ra0.y * sok; xa[2] = ra0.z * sok; xa[3] = ra0.w * sok;
        xa[4] = ra1.x * sok; xa[5] = ra1.y * sok; xa[6] = ra1.z * sok; xa[7] = ra1.w * sok;
        uint4 hv, lv;
        split8_pack(xa, hv, lv);
        *(uint4*)&AsH[bi][t * 8] = hv;
        *(uint4*)&AsL[bi][t * 8] = lv;
    };
    auto compute = [&](int bi, int b) {
#pragma unroll
        for (int mt = 0; mt < 4; ++mt) {
            short8 ah = *(const short8*)&AsH[bi][(mt * 64 + lane) * 8];
            short8 al = *(const short8*)&AsL[bi][(mt * 64 + lane) * 8];
#pragma unroll
            for (int q = 0; q < 4; ++q) {
                acc[mt][q] = __builtin_amdgcn_mfma_f32_16x16x32_bf16(ah, Bh[b][q], acc[mt][q], 0, 0, 0);
                acc[mt][q] = __builtin_amdgcn_mfma_f32_16x16x32_bf16(al, Bh[b][q], acc[mt][q], 0, 0, 0);
                acc[mt][q] = __builtin_amdgcn_mfma_f32_16x16x32_bf16(ah, Bl[b][q], acc[mt][q], 0, 0, 0);
            }
        }
    };

    // prologue: A(0), A(1) staged; B(0) in regs
    loadB(0, 0);
    loadA(0); writeA(0);
    loadA(1); writeA(1);
    __syncthreads();

#pragma unroll
    for (int kk = 0; kk < 8; ++kk) {
        if (kk < 7) loadB(kk + 1, (kk + 1) & 1);
        if (kk < 6) loadA(kk + 2);
        compute(kk % 3, kk & 1);
        if (kk < 6) writeA((kk + 2) % 3);
        softbar();
    }

    // epilogue: D row=(lane>>4)*4+reg, col=lane&15
    int r0 = (lane >> 4) * 4, c0 = lane & 15;
#pragma unroll
    for (int mt = 0; mt < 4; ++mt)
#pragma unroll
        for (int r = 0; r < 4; ++r) {
            int orow = i0 + mt * 16 + r0 + r;
            if (orow < n) {
#pragma unroll
                for (int q = 0; q < 4; ++q)
                    out[(size_t)orow * CH + wid * 64 + q * 16 + c0] = acc[mt][q][r];
            }
        }
}

// ---------------- mid layers sparse: 32 gathered rows/chunk, soft barriers ----------
__global__ __launch_bounds__(256) void sparse_mid_mfma_k(
        const float* __restrict__ x,
        const unsigned short* __restrict__ Whi,
        const unsigned short* __restrict__ Wlo,
        float* __restrict__ out, const int2* __restrict__ buckets,
        const int2* __restrict__ desc, const int* __restrict__ nchunks) {
    // A image: [kk(8)][mt(2)][lane(64)][j(8)]
    __shared__ unsigned short As_hi[8192];
    __shared__ unsigned short As_lo[8192];
    __shared__ int ii[PCH];
    int nc = *nchunks;
    int t = threadIdx.x;
    int wid = t >> 6, lane = t & 63;
    int r = t >> 3, kk0 = t & 7;          // 8 threads per gathered row
    int mt_s = r >> 4, rl = r & 15;
    for (int m = blockIdx.x; m < nc; m += gridDim.x) {
        int2 d = desc[m];
        int k = d.y >> 8, len = d.y & 255;
        // ---- stage A (full K=256 for 32 rows), split hi/lo ----
        if (r < len) {
            int2 pr = buckets[d.x + r];
            if (kk0 == 0) ii[r] = pr.x;
            const float* src = x + (size_t)pr.y * CH + kk0 * 32;
#pragma unroll
            for (int kg = 0; kg < 4; ++kg) {
                float xa[8];
                floatx4 v0 = *(const floatx4*)(src + kg * 8);
                floatx4 v1 = *(const floatx4*)(src + kg * 8 + 4);
                xa[0] = v0.x; xa[1] = v0.y; xa[2] = v0.z; xa[3] = v0.w;
                xa[4] = v1.x; xa[5] = v1.y; xa[6] = v1.z; xa[7] = v1.w;
                uint4 hv, lv;
                split8_pack(xa, hv, lv);
                int ab = ((kk0 * 2 + mt_s) * 64 + kg * 16 + rl) * 8;
                *(uint4*)&As_hi[ab] = hv;
                *(uint4*)&As_lo[ab] = lv;
            }
        } else {
            if (kk0 == 0) ii[r] = -1;
            uint4 z = {0, 0, 0, 0};
#pragma unroll
            for (int kg = 0; kg < 4; ++kg) {
                int ab = ((kk0 * 2 + mt_s) * 64 + kg * 16 + rl) * 8;
                *(uint4*)&As_hi[ab] = z;
                *(uint4*)&As_lo[ab] = z;
            }
        }
        softbar();
        floatx4 acc[2][4];
#pragma unroll
        for (int a = 0; a < 2; ++a)
#pragma unroll
            for (int b = 0; b < 4; ++b) acc[a][b] = floatx4{0.f, 0.f, 0.f, 0.f};

        short8 bh[2][4], bl[2][4];
        auto loadBs = [&](int kk, int b) {
#pragma unroll
            for (int q = 0; q < 4; ++q) {
                size_t off = (((size_t)(k * 8 + kk) * 16 + wid * 4 + q) * 64 + lane) * 8;
                bh[b][q] = *(const short8*)&Whi[off];
                bl[b][q] = *(const short8*)&Wlo[off];
            }
        };
        loadBs(0, 0);
#pragma unroll
        for (int kk = 0; kk < 8; ++kk) {
            if (kk < 7) loadBs(kk + 1, (kk + 1) & 1);
            int b = kk & 1;
            short8 ah0 = *(const short8*)&As_hi[((kk * 2 + 0) * 64 + lane) * 8];
            short8 al0 = *(const short8*)&As_lo[((kk * 2 + 0) * 64 + lane) * 8];
            short8 ah1 = *(const short8*)&As_hi[((kk * 2 + 1) * 64 + lane) * 8];
            short8 al1 = *(const short8*)&As_lo[((kk * 2 + 1) * 64 + lane) * 8];
#pragma unroll
            for (int q = 0; q < 4; ++q) {
                acc[0][q] = __builtin_amdgcn_mfma_f32_16x16x32_bf16(ah0, bh[b][q], acc[0][q], 0, 0, 0);
                acc[0][q] = __builtin_amdgcn_mfma_f32_16x16x32_bf16(al0, bh[b][q], acc[0][q], 0, 0, 0);
                acc[0][q] = __builtin_amdgcn_mfma_f32_16x16x32_bf16(ah0, bl[b][q], acc[0][q], 0, 0, 0);
                acc[1][q] = __builtin_amdgcn_mfma_f32_16x16x32_bf16(ah1, bh[b][q], acc[1][q], 0, 0, 0);
                acc[1][q] = __builtin_amdgcn_mfma_f32_16x16x32_bf16(al1, bh[b][q], acc[1][q], 0, 0, 0);
                acc[1][q] = __builtin_amdgcn_mfma_f32_16x16x32_bf16(ah1, bl[b][q], acc[1][q], 0, 0, 0);
            }
        }
        // ---- epilogue: atomic accumulate ----
        int r0 = (lane >> 4) * 4, c0 = lane & 15;
#pragma unroll
        for (int mt = 0; mt < 2; ++mt)
#pragma unroll
            for (int rr = 0; rr < 4; ++rr) {
                int orow = mt * 16 + r0 + rr;
                int i = ii[orow];
                if (i >= 0) {
#pragma unroll
                    for (int q = 0; q < 4; ++q)
                        atomicAdd(&out[(size_t)i * CH + wid * 64 + q * 16 + c0], acc[mt][q][rr]);
                }
            }
        softbar();
    }
}

// ---------------- layer 4: 256 -> 2 ----------------
__device__ inline float wave_sum(float v) {
    for (int off = 32; off; off >>= 1) v += __shfl_xor(v, off);
    return v;
}

__global__ void dense4_k(const float* __restrict__ x, const float* __restrict__ Wc,
                         float* __restrict__ out, int n) {
    int wid = threadIdx.x >> 6, lane = threadIdx.x & 63;
    int i = blockIdx.x * 4 + wid;
    if (i >= n) return;
    floatx4 xv = *reinterpret_cast<const floatx4*>(x + (size_t)i * CH + lane * 4);
    floatx4 w0 = *reinterpret_cast<const floatx4*>(Wc + lane * 8);
    floatx4 w1 = *reinterpret_cast<const floatx4*>(Wc + lane * 8 + 4);
    float a0 = xv.x * w0.x + xv.y * w0.z + xv.z * w1.x + xv.w * w1.z;
    float a1 = xv.x * w0.y + xv.y * w0.w + xv.z * w1.y + xv.w * w1.w;
    a0 = wave_sum(a0);
    a1 = wave_sum(a1);
    if (lane == 0) { out[2 * i] = a0; out[2 * i + 1] = a1; }
}

__global__ void sparse4b_k(const float* __restrict__ x, const float* __restrict__ W4,
                           float* __restrict__ out, const int2* __restrict__ buckets,
                           const int2* __restrict__ desc, const int* __restrict__ nchunks) {
    int nc = *nchunks;
    int wid = threadIdx.x >> 6, lane = threadIdx.x & 63;
    for (int m = blockIdx.x; m < nc; m += gridDim.x) {
        int2 d = desc[m];
        int k = d.y >> 8, len = d.y & 255;
        const float* Wk = W4 + (size_t)k * CH * 2;
        floatx4 w0 = *reinterpret_cast<const floatx4*>(Wk + lane * 8);
        floatx4 w1 = *reinterpret_cast<const floatx4*>(Wk + lane * 8 + 4);
        for (int p = wid; p < len; p += 4) {
            int2 pr = buckets[d.x + p];
            floatx4 xv = *reinterpret_cast<const floatx4*>(x + (size_t)pr.y * CH + lane * 4);
            float a0 = xv.x * w0.x + xv.y * w0.z + xv.z * w1.x + xv.w * w1.z;
            float a1 = xv.x * w0.y + xv.y * w0.w + xv.z * w1.y + xv.w * w1.w;
            a0 = wave_sum(a0);
            a1 = wave_sum(a1);
            if (lane == 0) {
                atomicAdd(&out[2 * pr.x], a0);
                atomicAdd(&out[2 * pr.x + 1], a1);
            }
        }
    }
}

extern "C" void kernel_launch(void* const* d_in, const int* in_sizes, int n_in,
                              void* d_out, int out_size, void* d_ws, size_t ws_size,
                              hipStream_t stream) {
    const int* coords = (const int*)d_in[0];
    const float* feats = (const float*)d_in[1];
    const float* W1 = (const float*)d_in[2];
    const float* W2 = (const float*)d_in[3];
    const float* W3 = (const float*)d_in[4];
    const float* W4 = (const float*)d_in[5];
    float* out = (float*)d_out;
    int n = in_sizes[0] / 3;

    char* ws = (char*)d_ws;
    auto alloc = [&](size_t bytes) -> void* {
        void* p = (void*)ws;
        ws += (bytes + 255) & ~(size_t)255;
        return p;
    };
    ull* tbl = (ull*)alloc((size_t)HASH_SIZE * 8);
    unsigned* bm = (unsigned*)alloc((size_t)BM_WORDS * 4);   // bm..kcnt contiguous: one memset
    int* kcnt = (int*)alloc((size_t)NSEG * 16 * 4);          // 1 counter per 64B line
    unsigned* keys = (unsigned*)alloc((size_t)n * 4);
    int* nchunks = (int*)alloc(4);
    int ndesc = NSEG * (SEGCAP / PCH);
    int2* desc = (int2*)alloc(sizeof(int2) * (size_t)ndesc);
    int2* buckets = (int2*)alloc(sizeof(int2) * (size_t)NSEG * SEGCAP);
    unsigned short* Whi2 = (unsigned short*)alloc((size_t)27 * 65536 * 2);
    unsigned short* Wlo2 = (unsigned short*)alloc((size_t)27 * 65536 * 2);
    unsigned short* Whi3 = (unsigned short*)alloc((size_t)27 * 65536 * 2);
    unsigned short* Wlo3 = (unsigned short*)alloc((size_t)27 * 65536 * 2);
    float* x1 = (float*)alloc((size_t)n * CH * 4);
    float* x2 = (float*)alloc((size_t)n * CH * 4);

    hipMemsetAsync(tbl, 0xFF, (size_t)HASH_SIZE * 8, stream);
    hipMemsetAsync(bm, 0, (size_t)BM_WORDS * 4 + (size_t)NSEG * 16 * 4, stream);

    hash_insert_k<<<(n + 255) / 256, 256, 0, stream>>>(coords, n, tbl, keys, bm);
    neighbor_bm_k<<<(n * 9 + 255) / 256, 256, 0, stream>>>(keys, n, bm, tbl, buckets, kcnt);
    chunk_desc_k<<<1, 256, 0, stream>>>(kcnt, desc, nchunks);
    prep_w_all_k<<<(2 * 27 * 8 * 256) / 256, 256, 0, stream>>>(W2, W3, Whi2, Wlo2, Whi3, Wlo3);

    int mtiles = (n + 63) / 64;

    // layer 1: 2 -> 256
    dense1_k<<<(n * CH + 255) / 256, 256, 0, stream>>>(feats, W1 + 13 * 2 * CH, x1, n);
    sparse1b_k<<<1024, 256, 0, stream>>>(feats, W1, x1, buckets, desc, nchunks);

    // layer 2: 256 -> 256
    dense_mid_mfma_k<<<mtiles, 256, 0, stream>>>(x1, Whi2 + (size_t)13 * 65536,
                                                 Wlo2 + (size_t)13 * 65536, x2, n);
    sparse_mid_mfma_k<<<512, 256, 0, stream>>>(x1, Whi2, Wlo2, x2, buckets, desc, nchunks);

    // layer 3: 256 -> 256
    dense_mid_mfma_k<<<mtiles, 256, 0, stream>>>(x2, Whi3 + (size_t)13 * 65536,
                                                 Wlo3 + (size_t)13 * 65536, x1, n);
    sparse_mid_mfma_k<<<512, 256, 0, stream>>>(x2, Whi3, Wlo3, x1, buckets, desc, nchunks);

    // layer 4: 256 -> 2
    dense4_k<<<(n + 3) / 4, 256, 0, stream>>>(x1, W4 + 13 * CH * 2, out, n);
    sparse4b_k<<<512, 256, 0, stream>>>(x1, W4, out, buckets, desc, nchunks);
}

// Round 14
// 252.632 us; speedup vs baseline: 1.1241x; 1.1241x over previous
//
#include <hip/hip_runtime.h>

#define HASH_BITS 19
#define HASH_SIZE (1u << HASH_BITS)
#define HASH_MASK (HASH_SIZE - 1)
#define CH 256
#define PCH 32       // pairs per chunk in bucketed sparse kernels
#define NREP 8       // counter/bucket replicas (atomic de-contention)
#define NSEG (27 * NREP)
#define SEGCAP 4096  // pairs per (k,rep) segment
#define BM_WORDS 536704  // ceil(258^3 / 32), padded
#define GD1 4096     // dense1 grid-stride blocks (front fusion)
#define GH  391      // hash blocks for n=100k (computed at runtime)
#define GD4 2048     // dense4 grid-stride blocks (back fusion)
#define GS4 512      // sparse4 blocks

typedef __attribute__((ext_vector_type(8))) short short8;
typedef __attribute__((ext_vector_type(4))) float floatx4;
typedef unsigned long long ull;

// packed f32x2 -> bf16x2 (src0 in low half) via HW cvt
__device__ __forceinline__ unsigned cvt_pk_bf16(float a, float b) {
    unsigned r;
    asm("v_cvt_pk_bf16_f32 %0, %1, %2" : "=v"(r) : "v"(a), "v"(b));
    return r;
}

// split 8 fp32 -> packed bf16 hi + bf16 lo (x ~= hi + lo; lo compensates hi's rounding)
__device__ inline void split8_pack(const float* xa, uint4& hv, uint4& lv) {
#pragma unroll
    for (int p = 0; p < 4; ++p) {
        unsigned hp = cvt_pk_bf16(xa[2 * p], xa[2 * p + 1]);
        float h0 = __uint_as_float(hp << 16);
        float h1 = __uint_as_float(hp & 0xFFFF0000u);
        unsigned lp = cvt_pk_bf16(xa[2 * p] - h0, xa[2 * p + 1] - h1);
        ((unsigned*)&hv)[p] = hp;
        ((unsigned*)&lv)[p] = lv.x * 0 + lp;  // keep simple assignment
    }
}

// (clean version without the hack above)
__device__ inline void split8_pack2(const float* xa, uint4& hv, uint4& lv) {
    unsigned hp[4], lp[4];
#pragma unroll
    for (int p = 0; p < 4; ++p) {
        hp[p] = cvt_pk_bf16(xa[2 * p], xa[2 * p + 1]);
        float h0 = __uint_as_float(hp[p] << 16);
        float h1 = __uint_as_float(hp[p] & 0xFFFF0000u);
        lp[p] = cvt_pk_bf16(xa[2 * p] - h0, xa[2 * p + 1] - h1);
    }
    hv.x = hp[0]; hv.y = hp[1]; hv.z = hp[2]; hv.w = hp[3];
    lv.x = lp[0]; lv.y = lp[1]; lv.z = lp[2]; lv.w = lp[3];
}

// ---------------- FRONT FUSION: dense1 | hash_insert | prep_w (independent) ----------
// empty hash sentinel = 0 (real keys >= 258*258+258+1 > 0, so entry 0 unreachable)
__global__ void front_fused_k(const int* __restrict__ coords, int n, int gh,
                              ull* __restrict__ tbl, unsigned* __restrict__ keys,
                              unsigned* __restrict__ bm,
                              const float* __restrict__ feats, const float* __restrict__ W1c,
                              float* __restrict__ x1,
                              const float* __restrict__ W2, const float* __restrict__ W3,
                              unsigned short* __restrict__ Whi2, unsigned short* __restrict__ Wlo2,
                              unsigned short* __restrict__ Whi3, unsigned short* __restrict__ Wlo3) {
    int b = blockIdx.x;
    int t = threadIdx.x;
    if (b < GD1) {
        // ---- dense1: layer-1 center (Cin=2), grid-stride rows, W hoisted ----
        float w0 = W1c[t], w1 = W1c[CH + t];
        for (int i = b; i < n; i += GD1) {
            float2 xv = *reinterpret_cast<const float2*>(feats + 2 * i);
            x1[(size_t)i * CH + t] = fmaf(xv.x, w0, xv.y * w1);
        }
        return;
    }
    b -= GD1;
    if (b < gh) {
        // ---- hash insert + bitmap + key cache ----
        int i = b * 256 + t;
        if (i >= n) return;
        unsigned cx = (unsigned)(coords[3 * i + 0] + 1);
        unsigned cy = (unsigned)(coords[3 * i + 1] + 1);
        unsigned cz = (unsigned)(coords[3 * i + 2] + 1);
        unsigned key = (cx * 258u + cy) * 258u + cz;
        keys[i] = key;
        atomicOr(&bm[key >> 5], 1u << (key & 31));
        ull e = ((ull)key << 32) | (unsigned)i;
        unsigned h = (key * 2654435761u) & HASH_MASK;
        while (true) {
            ull prev = atomicCAS(&tbl[h], 0ull, e);
            if (prev == 0ull) return;
            h = (h + 1) & HASH_MASK;
        }
    }
    b -= gh;
    {
        // ---- prep_w: split W2/W3 into fragment-ordered bf16 hi/lo images ----
        int tt0 = b * 256 + t;
        const int HALF = 27 * 8 * 256;
        if (tt0 >= 2 * HALF) return;
        const float* W = (tt0 < HALF) ? W2 : W3;
        unsigned short* Whi = (tt0 < HALF) ? Whi2 : Whi3;
        unsigned short* Wlo = (tt0 < HALF) ? Wlo2 : Wlo3;
        int tt = (tt0 < HALF) ? tt0 : tt0 - HALF;
        int cout = tt & 255, kk = (tt >> 8) & 7, k = tt >> 11;
        int nt = cout >> 4, lc = cout & 15;
        const float* src = W + (size_t)k * 65536 + (size_t)kk * 32 * 256 + cout;
        size_t dbase = (((size_t)(k * 8 + kk) * 16 + nt) * 64 + lc) * 8;
#pragma unroll
        for (int kg = 0; kg < 4; ++kg) {
            float xa[8];
#pragma unroll
            for (int j = 0; j < 8; ++j) xa[j] = src[(size_t)(kg * 8 + j) * 256];
            uint4 hv, lv;
            split8_pack2(xa, hv, lv);
            *(uint4*)(Whi + dbase + (size_t)kg * 16 * 8) = hv;
            *(uint4*)(Wlo + dbase + (size_t)kg * 16 * 8) = lv;
        }
    }
}

// ---------------- neighbor pairs: bitmap prefilter, replicated counters ----------------
__global__ void neighbor_bm_k(const unsigned* __restrict__ keys, int n,
                              const unsigned* __restrict__ bm,
                              const ull* __restrict__ tbl,
                              int2* __restrict__ buckets, int* __restrict__ kcnt) {
    int t = blockIdx.x * blockDim.x + threadIdx.x;
    if (t >= n * 9) return;
    int rep = blockIdx.x & (NREP - 1);
    int i = t / 9, r = t - i * 9;            // r = (dx+1)*3 + (dy+1)
    unsigned key = keys[i];
    int base = (int)key + ((r / 3 - 1) * 258 + (r % 3 - 1)) * 258;
    unsigned bA = base - 1, bB = base, bC = base + 1;
    unsigned hit0 = (bm[bA >> 5] >> (bA & 31)) & 1u;
    unsigned hit1 = (bm[bB >> 5] >> (bB & 31)) & 1u;
    unsigned hit2 = (bm[bC >> 5] >> (bC & 31)) & 1u;
#pragma unroll
    for (int dz = -1; dz <= 1; ++dz) {
        if (r == 4 && dz == 0) continue;     // center handled densely
        unsigned hit = dz < 0 ? hit0 : (dz == 0 ? hit1 : hit2);
        if (!hit) continue;
        unsigned nk = (unsigned)(base + dz);
        unsigned h = (nk * 2654435761u) & HASH_MASK;
        int j = -1;
        while (true) {
            ull e = tbl[h];
            if ((unsigned)(e >> 32) == nk) { j = (int)(e & 0xFFFFFFFFu); break; }
            if (e == 0ull) break;
            h = (h + 1) & HASH_MASK;
        }
        if (j >= 0) {
            int kk = 3 * r + dz + 1;
            int seg = kk * NREP + rep;
            int pos = atomicAdd(&kcnt[seg * 16], 1);
            buckets[(size_t)seg * SEGCAP + pos] = make_int2(i, j);
        }
    }
}

// ---------------- chunk descriptors over NSEG segments ----------------
__global__ void chunk_desc_k(const int* __restrict__ kcnt,
                             int2* __restrict__ desc, int* __restrict__ nchunks) {
    __shared__ int cnts[NSEG];
    __shared__ int offs[NSEG + 1];
    int t = threadIdx.x;
    if (t < NSEG) cnts[t] = kcnt[t * 16];
    __syncthreads();
    if (t == 0) {
        int acc = 0;
        for (int s = 0; s < NSEG; ++s) { offs[s] = acc; acc += (cnts[s] + PCH - 1) / PCH; }
        offs[NSEG] = acc;
        *nchunks = acc;
    }
    __syncthreads();
    if (t < NSEG) {
        int cnt = cnts[t];
        int o = offs[t];
        int k = t / NREP;
        for (int c = 0; c * PCH < cnt; ++c) {
            int len = min(PCH, cnt - c * PCH);
            desc[o + c] = make_int2(t * SEGCAP + c * PCH, (k << 8) | len);
        }
    }
}

__global__ void sparse1b_k(const float* __restrict__ feats, const float* __restrict__ W1,
                           float* __restrict__ out, const int2* __restrict__ buckets,
                           const int2* __restrict__ desc, const int* __restrict__ nchunks) {
    __shared__ float xs[PCH][2];
    __shared__ int ii[PCH];
    int nc = *nchunks;
    int t = threadIdx.x;
    for (int m = blockIdx.x; m < nc; m += gridDim.x) {
        int2 d = desc[m];
        int k = d.y >> 8, len = d.y & 255;
        if (t < PCH) {
            if (t < len) {
                int2 pr = buckets[d.x + t];
                ii[t] = pr.x;
                xs[t][0] = feats[2 * pr.y];
                xs[t][1] = feats[2 * pr.y + 1];
            } else {
                ii[t] = -1;
                xs[t][0] = 0.f; xs[t][1] = 0.f;
            }
        }
        __syncthreads();
        const float* Wk = W1 + (size_t)k * 2 * CH;
        float w0 = Wk[t], w1 = Wk[CH + t];
#pragma unroll
        for (int p = 0; p < PCH; ++p) {
            int i = ii[p];
            if (i >= 0) atomicAdd(&out[(size_t)i * CH + t], fmaf(xs[p][0], w0, xs[p][1] * w1));
        }
        __syncthreads();
    }
}

// ---------------- mid layers dense center: M=64, A triple-buffer, 1 barrier/kk ----------
__global__ __launch_bounds__(256, 3) void dense_mid_mfma_k(
        const float* __restrict__ x,
        const unsigned short* __restrict__ Whi,
        const unsigned short* __restrict__ Wlo,
        float* __restrict__ out, int n) {
    __shared__ unsigned short AsH[3][2048], AsL[3][2048];
    int t = threadIdx.x;
    int wid = t >> 6, lane = t & 63;
    int i0 = blockIdx.x * 64;

    floatx4 acc[4][4];
#pragma unroll
    for (int a = 0; a < 4; ++a)
#pragma unroll
        for (int b = 0; b < 4; ++b) acc[a][b] = floatx4{0.f, 0.f, 0.f, 0.f};

    // staging role: thread t -> slot t: row = (t>>6)*16 + (t&15), kg = (t>>4)&3
    int row = ((t >> 6) << 4) + (t & 15);
    int kg = (t >> 4) & 3;
    float sok = (i0 + row < n) ? 1.f : 0.f;
    const float* sp = x + (size_t)min(i0 + row, n - 1) * CH + kg * 8;

    floatx4 ra0, ra1;
    short8 Bh[2][4], Bl[2][4];

    auto loadB = [&](int kk, int b) {
#pragma unroll
        for (int q = 0; q < 4; ++q) {
            size_t off = (((size_t)kk * 16 + wid * 4 + q) * 64 + lane) * 8;
            Bh[b][q] = *(const short8*)&Whi[off];
            Bl[b][q] = *(const short8*)&Wlo[off];
        }
    };
    auto loadA = [&](int kk) {
        ra0 = *(const floatx4*)(sp + kk * 32);
        ra1 = *(const floatx4*)(sp + kk * 32 + 4);
    };
    auto writeA = [&](int bi) {
        float xa[8];
        xa[0] = ra0.x * sok; xa[1] = ra0.y * sok; xa[2] = ra0.z * sok; xa[3] = ra0.w * sok;
        xa[4] = ra1.x * sok; xa[5] = ra1.y * sok; xa[6] = ra1.z * sok; xa[7] = ra1.w * sok;
        uint4 hv, lv;
        split8_pack2(xa, hv, lv);
        *(uint4*)&AsH[bi][t * 8] = hv;
        *(uint4*)&AsL[bi][t * 8] = lv;
    };
    auto compute = [&](int bi, int b) {
#pragma unroll
        for (int mt = 0; mt < 4; ++mt) {
            short8 ah = *(const short8*)&AsH[bi][(mt * 64 + lane) * 8];
            short8 al = *(const short8*)&AsL[bi][(mt * 64 + lane) * 8];
#pragma unroll
            for (int q = 0; q < 4; ++q) {
                acc[mt][q] = __builtin_amdgcn_mfma_f32_16x16x32_bf16(ah, Bh[b][q], acc[mt][q], 0, 0, 0);
                acc[mt][q] = __builtin_amdgcn_mfma_f32_16x16x32_bf16(al, Bh[b][q], acc[mt][q], 0, 0, 0);
                acc[mt][q] = __builtin_amdgcn_mfma_f32_16x16x32_bf16(ah, Bl[b][q], acc[mt][q], 0, 0, 0);
            }
        }
    };

    // prologue: A(0), A(1) staged; B(0) in regs
    loadB(0, 0);
    loadA(0); writeA(0);
    loadA(1); writeA(1);
    __syncthreads();

#pragma unroll
    for (int kk = 0; kk < 8; ++kk) {
        if (kk < 7) loadB(kk + 1, (kk + 1) & 1);
        if (kk < 6) loadA(kk + 2);
        compute(kk % 3, kk & 1);
        if (kk < 6) writeA((kk + 2) % 3);
        __syncthreads();
    }

    // epilogue: D row=(lane>>4)*4+reg, col=lane&15
    int r0 = (lane >> 4) * 4, c0 = lane & 15;
#pragma unroll
    for (int mt = 0; mt < 4; ++mt)
#pragma unroll
        for (int r = 0; r < 4; ++r) {
            int orow = i0 + mt * 16 + r0 + r;
            if (orow < n) {
#pragma unroll
                for (int q = 0; q < 4; ++q)
                    out[(size_t)orow * CH + wid * 64 + q * 16 + c0] = acc[mt][q][r];
            }
        }
}

// ---------------- mid layers sparse: 32 gathered rows/chunk, B-prefetch kk loop ----------
__global__ __launch_bounds__(256) void sparse_mid_mfma_k(
        const float* __restrict__ x,
        const unsigned short* __restrict__ Whi,
        const unsigned short* __restrict__ Wlo,
        float* __restrict__ out, const int2* __restrict__ buckets,
        const int2* __restrict__ desc, const int* __restrict__ nchunks) {
    // A image: [kk(8)][mt(2)][lane(64)][j(8)]
    __shared__ unsigned short As_hi[8192];
    __shared__ unsigned short As_lo[8192];
    __shared__ int ii[PCH];
    int nc = *nchunks;
    int t = threadIdx.x;
    int wid = t >> 6, lane = t & 63;
    int r = t >> 3, kk0 = t & 7;          // 8 threads per gathered row
    int mt_s = r >> 4, rl = r & 15;
    for (int m = blockIdx.x; m < nc; m += gridDim.x) {
        int2 d = desc[m];
        int k = d.y >> 8, len = d.y & 255;
        // ---- stage A (full K=256 for 32 rows), split hi/lo ----
        if (r < len) {
            int2 pr = buckets[d.x + r];
            if (kk0 == 0) ii[r] = pr.x;
            const float* src = x + (size_t)pr.y * CH + kk0 * 32;
#pragma unroll
            for (int kg = 0; kg < 4; ++kg) {
                float xa[8];
                floatx4 v0 = *(const floatx4*)(src + kg * 8);
                floatx4 v1 = *(const floatx4*)(src + kg * 8 + 4);
                xa[0] = v0.x; xa[1] = v0.y; xa[2] = v0.z; xa[3] = v0.w;
                xa[4] = v1.x; xa[5] = v1.y; xa[6] = v1.z; xa[7] = v1.w;
                uint4 hv, lv;
                split8_pack2(xa, hv, lv);
                int ab = ((kk0 * 2 + mt_s) * 64 + kg * 16 + rl) * 8;
                *(uint4*)&As_hi[ab] = hv;
                *(uint4*)&As_lo[ab] = lv;
            }
        } else {
            if (kk0 == 0) ii[r] = -1;
            uint4 z = {0, 0, 0, 0};
#pragma unroll
            for (int kg = 0; kg < 4; ++kg) {
                int ab = ((kk0 * 2 + mt_s) * 64 + kg * 16 + rl) * 8;
                *(uint4*)&As_hi[ab] = z;
                *(uint4*)&As_lo[ab] = z;
            }
        }
        __syncthreads();
        floatx4 acc[2][4];
#pragma unroll
        for (int a = 0; a < 2; ++a)
#pragma unroll
            for (int b = 0; b < 4; ++b) acc[a][b] = floatx4{0.f, 0.f, 0.f, 0.f};

        short8 bh[2][4], bl[2][4];
        auto loadBs = [&](int kk, int b) {
#pragma unroll
            for (int q = 0; q < 4; ++q) {
                size_t off = (((size_t)(k * 8 + kk) * 16 + wid * 4 + q) * 64 + lane) * 8;
                bh[b][q] = *(const short8*)&Whi[off];
                bl[b][q] = *(const short8*)&Wlo[off];
            }
        };
        loadBs(0, 0);
#pragma unroll
        for (int kk = 0; kk < 8; ++kk) {
            if (kk < 7) loadBs(kk + 1, (kk + 1) & 1);
            int b = kk & 1;
            short8 ah0 = *(const short8*)&As_hi[((kk * 2 + 0) * 64 + lane) * 8];
            short8 al0 = *(const short8*)&As_lo[((kk * 2 + 0) * 64 + lane) * 8];
            short8 ah1 = *(const short8*)&As_hi[((kk * 2 + 1) * 64 + lane) * 8];
            short8 al1 = *(const short8*)&As_lo[((kk * 2 + 1) * 64 + lane) * 8];
#pragma unroll
            for (int q = 0; q < 4; ++q) {
                acc[0][q] = __builtin_amdgcn_mfma_f32_16x16x32_bf16(ah0, bh[b][q], acc[0][q], 0, 0, 0);
                acc[0][q] = __builtin_amdgcn_mfma_f32_16x16x32_bf16(al0, bh[b][q], acc[0][q], 0, 0, 0);
                acc[0][q] = __builtin_amdgcn_mfma_f32_16x16x32_bf16(ah0, bl[b][q], acc[0][q], 0, 0, 0);
                acc[1][q] = __builtin_amdgcn_mfma_f32_16x16x32_bf16(ah1, bh[b][q], acc[1][q], 0, 0, 0);
                acc[1][q] = __builtin_amdgcn_mfma_f32_16x16x32_bf16(al1, bh[b][q], acc[1][q], 0, 0, 0);
                acc[1][q] = __builtin_amdgcn_mfma_f32_16x16x32_bf16(ah1, bl[b][q], acc[1][q], 0, 0, 0);
            }
        }
        // ---- epilogue: atomic accumulate ----
        int r0 = (lane >> 4) * 4, c0 = lane & 15;
#pragma unroll
        for (int mt = 0; mt < 2; ++mt)
#pragma unroll
            for (int rr = 0; rr < 4; ++rr) {
                int orow = mt * 16 + r0 + rr;
                int i = ii[orow];
                if (i >= 0) {
#pragma unroll
                    for (int q = 0; q < 4; ++q)
                        atomicAdd(&out[(size_t)i * CH + wid * 64 + q * 16 + c0], acc[mt][q][rr]);
                }
            }
        __syncthreads();
    }
}

// ---------------- BACK FUSION: dense4 (atomicAdd on pre-zeroed out) | sparse4b ----------
__device__ inline float wave_sum(float v) {
    for (int off = 32; off; off >>= 1) v += __shfl_xor(v, off);
    return v;
}

__global__ void back_fused_k(const float* __restrict__ x, const float* __restrict__ W4,
                             float* __restrict__ out, int n,
                             const int2* __restrict__ buckets,
                             const int2* __restrict__ desc, const int* __restrict__ nchunks) {
    int b = blockIdx.x;
    int wid = threadIdx.x >> 6, lane = threadIdx.x & 63;
    if (b < GD4) {
        // ---- dense4: center term, grid-stride, atomicAdd onto zeroed out ----
        const float* Wc = W4 + 13 * CH * 2;
        floatx4 w0 = *reinterpret_cast<const floatx4*>(Wc + lane * 8);
        floatx4 w1 = *reinterpret_cast<const floatx4*>(Wc + lane * 8 + 4);
        for (int i = b * 4 + wid; i < n; i += GD4 * 4) {
            floatx4 xv = *reinterpret_cast<const floatx4*>(x + (size_t)i * CH + lane * 4);
            float a0 = xv.x * w0.x + xv.y * w0.z + xv.z * w1.x + xv.w * w1.z;
            float a1 = xv.x * w0.y + xv.y * w0.w + xv.z * w1.y + xv.w * w1.w;
            a0 = wave_sum(a0);
            a1 = wave_sum(a1);
            if (lane == 0) {
                atomicAdd(&out[2 * i], a0);
                atomicAdd(&out[2 * i + 1], a1);
            }
        }
        return;
    }
    b -= GD4;
    // ---- sparse4b: neighbor terms ----
    int nc = *nchunks;
    for (int m = b; m < nc; m += GS4) {
        int2 d = desc[m];
        int k = d.y >> 8, len = d.y & 255;
        const float* Wk = W4 + (size_t)k * CH * 2;
        floatx4 w0 = *reinterpret_cast<const floatx4*>(Wk + lane * 8);
        floatx4 w1 = *reinterpret_cast<const floatx4*>(Wk + lane * 8 + 4);
        for (int p = wid; p < len; p += 4) {
            int2 pr = buckets[d.x + p];
            floatx4 xv = *reinterpret_cast<const floatx4*>(x + (size_t)pr.y * CH + lane * 4);
            float a0 = xv.x * w0.x + xv.y * w0.z + xv.z * w1.x + xv.w * w1.z;
            float a1 = xv.x * w0.y + xv.y * w0.w + xv.z * w1.y + xv.w * w1.w;
            a0 = wave_sum(a0);
            a1 = wave_sum(a1);
            if (lane == 0) {
                atomicAdd(&out[2 * pr.x], a0);
                atomicAdd(&out[2 * pr.x + 1], a1);
            }
        }
    }
}

extern "C" void kernel_launch(void* const* d_in, const int* in_sizes, int n_in,
                              void* d_out, int out_size, void* d_ws, size_t ws_size,
                              hipStream_t stream) {
    const int* coords = (const int*)d_in[0];
    const float* feats = (const float*)d_in[1];
    const float* W1 = (const float*)d_in[2];
    const float* W2 = (const float*)d_in[3];
    const float* W3 = (const float*)d_in[4];
    const float* W4 = (const float*)d_in[5];
    float* out = (float*)d_out;
    int n = in_sizes[0] / 3;

    char* ws = (char*)d_ws;
    auto alloc = [&](size_t bytes) -> void* {
        void* p = (void*)ws;
        ws += (bytes + 255) & ~(size_t)255;
        return p;
    };
    // tbl, bm, kcnt contiguous (all 256-multiples) -> single zero memset
    ull* tbl = (ull*)alloc((size_t)HASH_SIZE * 8);
    unsigned* bm = (unsigned*)alloc((size_t)BM_WORDS * 4);
    int* kcnt = (int*)alloc((size_t)NSEG * 16 * 4);
    unsigned* keys = (unsigned*)alloc((size_t)n * 4);
    int* nchunks = (int*)alloc(4);
    int ndesc = NSEG * (SEGCAP / PCH);
    int2* desc = (int2*)alloc(sizeof(int2) * (size_t)ndesc);
    int2* buckets = (int2*)alloc(sizeof(int2) * (size_t)NSEG * SEGCAP);
    unsigned short* Whi2 = (unsigned short*)alloc((size_t)27 * 65536 * 2);
    unsigned short* Wlo2 = (unsigned short*)alloc((size_t)27 * 65536 * 2);
    unsigned short* Whi3 = (unsigned short*)alloc((size_t)27 * 65536 * 2);
    unsigned short* Wlo3 = (unsigned short*)alloc((size_t)27 * 65536 * 2);
    float* x1 = (float*)alloc((size_t)n * CH * 4);
    float* x2 = (float*)alloc((size_t)n * CH * 4);

    size_t zspan = (size_t)HASH_SIZE * 8 + (size_t)BM_WORDS * 4 + (size_t)NSEG * 16 * 4;
    hipMemsetAsync(tbl, 0, zspan, stream);
    hipMemsetAsync(out, 0, (size_t)out_size * 4, stream);   // back-fusion needs zeroed out

    int gh = (n + 255) / 256;
    int gp = (2 * 27 * 8 * 256) / 256;
    front_fused_k<<<GD1 + gh + gp, 256, 0, stream>>>(
        coords, n, gh, tbl, keys, bm,
        feats, W1 + 13 * 2 * CH, x1,
        W2, W3, Whi2, Wlo2, Whi3, Wlo3);

    neighbor_bm_k<<<(n * 9 + 255) / 256, 256, 0, stream>>>(keys, n, bm, tbl, buckets, kcnt);
    chunk_desc_k<<<1, 256, 0, stream>>>(kcnt, desc, nchunks);
    sparse1b_k<<<1024, 256, 0, stream>>>(feats, W1, x1, buckets, desc, nchunks);

    int mtiles = (n + 63) / 64;

    // layer 2: 256 -> 256
    dense_mid_mfma_k<<<mtiles, 256, 0, stream>>>(x1, Whi2 + (size_t)13 * 65536,
                                                 Wlo2 + (size_t)13 * 65536, x2, n);
    sparse_mid_mfma_k<<<512, 256, 0, stream>>>(x1, Whi2, Wlo2, x2, buckets, desc, nchunks);

    // layer 3: 256 -> 256
    dense_mid_mfma_k<<<mtiles, 256, 0, stream>>>(x2, Whi3 + (size_t)13 * 65536,
                                                 Wlo3 + (size_t)13 * 65536, x1, n);
    sparse_mid_mfma_k<<<512, 256, 0, stream>>>(x2, Whi3, Wlo3, x1, buckets, desc, nchunks);

    // layer 4: 256 -> 2 (dense + sparse fused; out pre-zeroed)
    back_fused_k<<<GD4 + GS4, 256, 0, stream>>>(x1, W4, out, n, buckets, desc, nchunks);
}